// Round 14
// baseline (269.538 us; speedup 1.0000x reference)
//
#include <hip/hip_runtime.h>
#include <hip/hip_bf16.h>
#include <math.h>

#define NB 8192
#define NN 20
#define DD 128
#define HH 8
#define FFD 512
#define NROWS (NB * NN)          // 163840 total rows

typedef __attribute__((ext_vector_type(8))) short bf16x8;
typedef __attribute__((ext_vector_type(4))) float f32x4;
typedef __attribute__((ext_vector_type(2))) _Float16 h2;
typedef __attribute__((ext_vector_type(8))) _Float16 f16x8;

#if defined(__has_builtin)
#if __has_builtin(__builtin_amdgcn_fdot2)
#define FDOT2(a, b, c) __builtin_amdgcn_fdot2((a), (b), (c), false)
#endif
#endif
#ifndef FDOT2
#define FDOT2(a, b, c) (fmaf((float)(a).x, (float)(b).x, fmaf((float)(a).y, (float)(b).y, (c))))
#endif

__device__ __forceinline__ unsigned short f2bf(float f) {
  union { __hip_bfloat16 h; unsigned short u; } cv; cv.h = __float2bfloat16(f); return cv.u;
}
__device__ __forceinline__ float bf2f(unsigned short u) {
  union { unsigned short u; __hip_bfloat16 h; } cv; cv.u = u; return __bfloat162float(cv.h);
}
__device__ __forceinline__ unsigned short f2h_bits(float f) {
  union { _Float16 h; unsigned short u; } cv; cv.h = (_Float16)f; return cv.u;
}
__device__ __forceinline__ float h2f_bits(unsigned short u) {
  union { unsigned short u; _Float16 h; } cv; cv.u = u; return (float)cv.h;
}
// gelu tanh-form, 8 ops
__device__ __forceinline__ float gelu_t(float v) {
  float t  = v * v;
  float u2 = v * fmaf(0.0713548162f, t, 1.5957691216f);
  float e  = __expf(u2);
  float r  = __builtin_amdgcn_rcpf(e + 1.0f);
  return fmaf(-v, r, v);
}
// async global->LDS, 16B/lane
__device__ __forceinline__ void gload16(const unsigned short* g, unsigned short* lds) {
  __builtin_amdgcn_global_load_lds(
      (const __attribute__((address_space(1))) unsigned int*)g,
      (__attribute__((address_space(3))) unsigned int*)lds, 16, 0, 0);
}

// ======================= prep: weight frag swizzle + bias fuse (frozen) =======================
__global__ __launch_bounds__(256) void prep2(
    const float* __restrict__ wq, const float* __restrict__ wk, const float* __restrict__ wv,
    const float* __restrict__ w1, const float* __restrict__ w2, const float* __restrict__ wo,
    const float* __restrict__ rel, const float* __restrict__ gb, const float* __restrict__ alpha,
    unsigned short* __restrict__ WcF, unsigned short* __restrict__ w1F,
    unsigned short* __restrict__ w2F, unsigned short* __restrict__ woF,
    float* __restrict__ biasT)
{
  int bid = blockIdx.x, t = threadIdx.x;
  if (bid < 288) {
    int nt = bid / 12, kc = bid % 12;
    for (int i = t; i < 512; i += 256) {
      int lane = i >> 3, j = i & 7;
      int k = kc * 32 + (lane >> 4) * 8 + j;
      int c = nt * 16 + (lane & 15);
      int kk = k >> 7, din = k & 127;
      int which = c >> 7, dout = c & 127;
      const float* w = (which == 0) ? wq : (which == 1) ? wk : wv;
      WcF[((nt * 12 + kc) * 64 + lane) * 8 + j] = f2bf(w[(dout * 128 + din) * 3 + kk]);
    }
  } else if (bid < 416) {
    int tt = bid - 288; int nt = tt / 4, kc = tt % 4;
    for (int i = t; i < 512; i += 256) {
      int lane = i >> 3, j = i & 7;
      int k = kc * 32 + (lane >> 4) * 8 + j;
      int c = nt * 16 + (lane & 15);
      w1F[((nt * 4 + kc) * 64 + lane) * 8 + j] = f2bf(w1[k * 512 + c]);
    }
  } else if (bid < 544) {
    int tt = bid - 416; int nt = tt / 16, kc = tt % 16;
    for (int i = t; i < 512; i += 256) {
      int lane = i >> 3, j = i & 7;
      int k = kc * 32 + (lane >> 4) * 8 + j;
      int c = nt * 16 + (lane & 15);
      w2F[((nt * 16 + kc) * 64 + lane) * 8 + j] = f2bf(w2[k * 128 + c]);
    }
  } else if (bid < 576) {
    int tt = bid - 544; int nt = tt / 4, kc = tt % 4;
    for (int i = t; i < 512; i += 256) {
      int lane = i >> 3, j = i & 7;
      int k = kc * 32 + (lane >> 4) * 8 + j;
      int c = nt * 16 + (lane & 15);
      woF[((nt * 4 + kc) * 64 + lane) * 8 + j] = f2h_bits(wo[k * 128 + c]);   // fp16
    }
  } else {
    int h = bid - 576; float a = alpha[0];
    for (int i = t; i < 400; i += 256) {
      int n = i / 20, m = i % 20;
      biasT[h * 400 + i] = rel[(n - m + 19) * 8 + h] + gb[h * 400 + i] * a;
    }
  }
}

// ======================= conv1d-QKV v6 (R11-proven): fused q/k/v, __syncthreads pipeline ========
__global__ __launch_bounds__(256, 3) void conv_qkv(
    const float* __restrict__ x, const unsigned short* __restrict__ WcF,
    const float* __restrict__ lnq_w, const float* __restrict__ lnq_b,
    const float* __restrict__ lnk_w, const float* __restrict__ lnk_b,
    const float* __restrict__ lnv_w, const float* __restrict__ lnv_b,
    unsigned short* __restrict__ qP, unsigned short* __restrict__ kP,
    unsigned short* __restrict__ vP)
{
  __shared__ __align__(16) unsigned short xA[130 * 136];
  __shared__ __align__(16) unsigned short Bb[2][4096];
  unsigned short* Obuf = &Bb[0][0];

  const int t = threadIdx.x;
  const int w = t >> 6, l = t & 63;
  const int l15 = l & 15, l4 = l >> 4;
  const long g0 = (long)blockIdx.x * 128;
  const int chunkA = w * 2, chunkB = w * 2 + 1;

  gload16(WcF + (size_t)(chunkA * 12) * 512 + l * 8, &Bb[0][chunkA * 512]);
  gload16(WcF + (size_t)(chunkB * 12) * 512 + l * 8, &Bb[0][chunkB * 512]);

  for (int i = t; i < 130 * 32; i += 256) {
    int r = i >> 5, c4 = i & 31;
    long g = g0 - 1 + r;
    long gc = g < 0 ? 0 : (g >= NROWS ? NROWS - 1 : g);
    float4 v = *(const float4*)(x + gc * 128 + c4 * 4);
    ushort4 pk; pk.x = f2bf(v.x); pk.y = f2bf(v.y); pk.z = f2bf(v.z); pk.w = f2bf(v.w);
    *(ushort4*)&xA[r * 136 + c4 * 4] = pk;
  }
  __syncthreads();   // Bb[0] + xA ready

  const int rA0 = w * 32 + l15;
  const int rA1 = rA0 + 16;
  const int nA0 = (int)((g0 + rA0) % 20);
  const int nA1 = (int)((g0 + rA1) % 20);
  bool mk0[3], mk1[3];
  mk0[0] = (nA0 != 0);  mk0[1] = true; mk0[2] = (nA0 != 19);
  mk1[0] = (nA1 != 0);  mk1[1] = true; mk1[2] = (nA1 != 19);

  const bf16x8 zz = {};
  for (int p = 0; p < 3; ++p) {
    const size_t Wpo = (size_t)p * 8 * 12 * 512;

    f32x4 acc[2][8];
    #pragma unroll
    for (int mt = 0; mt < 2; ++mt)
      #pragma unroll
      for (int nt = 0; nt < 8; ++nt) acc[mt][nt] = (f32x4){0.f, 0.f, 0.f, 0.f};

    for (int kc = 0; kc < 12; ++kc) {
      if (kc < 11) {
        int nb = (kc + 1) & 1;
        gload16(WcF + Wpo + (size_t)(chunkA * 12 + kc + 1) * 512 + l * 8, &Bb[nb][chunkA * 512]);
        gload16(WcF + Wpo + (size_t)(chunkB * 12 + kc + 1) * 512 + l * 8, &Bb[nb][chunkB * 512]);
      }
      const int kk = kc >> 2, k4 = kc & 3;
      bf16x8 a0 = *(const bf16x8*)&xA[(rA0 + kk) * 136 + k4 * 32 + l4 * 8]; if (!mk0[kk]) a0 = zz;
      bf16x8 a1 = *(const bf16x8*)&xA[(rA1 + kk) * 136 + k4 * 32 + l4 * 8]; if (!mk1[kk]) a1 = zz;
      const unsigned short* bb = &Bb[kc & 1][l * 8];
      #pragma unroll
      for (int nt = 0; nt < 8; ++nt) {
        bf16x8 b = *(const bf16x8*)(bb + nt * 512);
        acc[0][nt] = __builtin_amdgcn_mfma_f32_16x16x32_bf16(a0, b, acc[0][nt], 0, 0, 0);
        acc[1][nt] = __builtin_amdgcn_mfma_f32_16x16x32_bf16(a1, b, acc[1][nt], 0, 0, 0);
      }
      __syncthreads();   // drains slab kc+1 + WAR on Bb
    }

    const float* lw = (p == 0) ? lnq_w : (p == 1) ? lnk_w : lnv_w;
    const float* lb = (p == 0) ? lnq_b : (p == 1) ? lnk_b : lnv_b;
    const float qs = (p == 0) ? 0.25f : 1.0f;
    unsigned short* plane = (p == 0) ? qP : (p == 1) ? kP : vP;
    float gw8[8], gb8[8];
    #pragma unroll
    for (int nt = 0; nt < 8; ++nt) { gw8[nt] = lw[nt * 16 + l15]; gb8[nt] = lb[nt * 16 + l15]; }

    float meanv[2][4], invv[2][4];
    #pragma unroll
    for (int mt = 0; mt < 2; ++mt) {
      float s[4], qq[4];
      #pragma unroll
      for (int j = 0; j < 4; ++j) {
        float a0 = 0.f, a1 = 0.f;
        #pragma unroll
        for (int nt = 0; nt < 8; ++nt) { float v = acc[mt][nt][j]; a0 += v; a1 = fmaf(v, v, a1); }
        s[j] = a0; qq[j] = a1;
      }
      #pragma unroll
      for (int off = 1; off < 16; off <<= 1) {
        #pragma unroll
        for (int j = 0; j < 4; ++j) { s[j] += __shfl_xor(s[j], off); qq[j] += __shfl_xor(qq[j], off); }
      }
      #pragma unroll
      for (int j = 0; j < 4; ++j) {
        float mean = s[j] * (1.f / 128.f);
        float var  = qq[j] * (1.f / 128.f) - mean * mean;
        meanv[mt][j] = mean;
        invv[mt][j]  = rsqrtf(var + 1e-5f);
      }
    }

    #pragma unroll
    for (int q = 0; q < 2; ++q) {
      #pragma unroll
      for (int mt = 0; mt < 2; ++mt)
        #pragma unroll
        for (int j = 0; j < 4; ++j) {
          int lr = w * 32 + mt * 16 + l4 * 4 + j;
          #pragma unroll
          for (int ntl = 0; ntl < 4; ++ntl) {
            int nt = q * 4 + ntl;
            Obuf[lr * 64 + ntl * 16 + l15] =
                f2bf((acc[mt][nt][j] - meanv[mt][j]) * invv[mt][j] * gw8[nt] + gb8[nt]);
          }
        }
      __syncthreads();
      #pragma unroll
      for (int it = 0; it < 4; ++it) {
        int i = t + it * 256;
        int r = i >> 3, c8 = i & 7;
        bf16x8 ob = *(const bf16x8*)&Obuf[r * 64 + c8 * 8];
        bf16x8 xr8 = *(const bf16x8*)&xA[(r + 1) * 136 + q * 64 + c8 * 8];
        unsigned short o[8];
        #pragma unroll
        for (int j = 0; j < 8; ++j)
          o[j] = f2h_bits((bf2f((unsigned short)xr8[j]) + bf2f((unsigned short)ob[j])) * qs);  // fp16
        *(bf16x8*)&plane[(g0 + r) * 128 + q * 64 + c8 * 8] = *(const bf16x8*)o;
      }
      __syncthreads();
    }

    if (p < 2) {
      size_t Wn = (size_t)(p + 1) * 8 * 12 * 512;
      gload16(WcF + Wn + (size_t)(chunkA * 12) * 512 + l * 8, &Bb[0][chunkA * 512]);
      gload16(WcF + Wn + (size_t)(chunkB * 12) * 512 + l * 8, &Bb[0][chunkB * 512]);
      __syncthreads();
    }
  }
}

// ======================= attn_wo v5 (R11-proven): FP16 data path, dot2/pk_fma ===================
__global__ __launch_bounds__(256, 3) void attn_wo(
    const float* __restrict__ x,
    const unsigned short* __restrict__ qP, const unsigned short* __restrict__ kP,
    const unsigned short* __restrict__ vP,
    const unsigned short* __restrict__ woF, const float* __restrict__ biasT,
    const float* __restrict__ bo,
    const float* __restrict__ n1w, const float* __restrict__ n1b,
    unsigned short* __restrict__ xr)
{
  __shared__ __align__(16) char smem[43520];
  unsigned short* ks  = (unsigned short*)smem;
  unsigned short* vs  = (unsigned short*)(smem + 21760);
  unsigned short* ctx = ks;
  unsigned short* scr = vs;

  const int t = threadIdx.x;
  const int w = t >> 6, l = t & 63;
  const int l15 = l & 15, l4 = l >> 4;
  const int eb = blockIdx.x * 4;

  for (int i = t; i < 2560; i += 256) {
    int proj = i / 1280, r = i % 1280;
    int e = r / 320, rr = r % 320;
    int n = rr / 16, c8 = rr % 16;
    const unsigned short* src = (proj == 0 ? kP : vP) + (((size_t)(eb + e) * 20 + n) * 128 + c8 * 8);
    unsigned short* dst = (proj == 0 ? ks : vs) + ((e * 20 + n) * 136 + c8 * 8);
    *(bf16x8*)dst = *(const bf16x8*)src;
  }
  __syncthreads();

  float pm[3][20];
  #pragma unroll
  for (int pass = 0; pass < 3; ++pass) {
    int i = t + pass * 256;
    if (i < 640) {
      int e = i / 160, hh = (i / 20) % 8, n = i % 20;
      const unsigned short* qr = qP + ((size_t)(eb + e) * 20 + n) * 128 + hh * 16;
      f16x8 qa = *(const f16x8*)qr;
      f16x8 qb = *(const f16x8*)(qr + 8);
      h2 qp[8];
      #pragma unroll
      for (int j = 0; j < 4; ++j) {
        qp[j]     = (h2){qa[2 * j], qa[2 * j + 1]};
        qp[4 + j] = (h2){qb[2 * j], qb[2 * j + 1]};
      }
      float bias[20];
      const float* bp = &biasT[(hh * 20 + n) * 20];
      #pragma unroll
      for (int m4 = 0; m4 < 5; ++m4) {
        float4 bv = *(const float4*)(bp + m4 * 4);
        bias[m4 * 4] = bv.x; bias[m4 * 4 + 1] = bv.y; bias[m4 * 4 + 2] = bv.z; bias[m4 * 4 + 3] = bv.w;
      }
      float mx = -1e30f;
      #pragma unroll
      for (int m = 0; m < 20; ++m) {
        const unsigned short* kr = &ks[(e * 20 + m) * 136 + hh * 16];
        f16x8 ka = *(const f16x8*)kr;
        f16x8 kb = *(const f16x8*)(kr + 8);
        float s0 = FDOT2(qp[0], ((h2){ka[0], ka[1]}), bias[m]);
        float s1 = FDOT2(qp[1], ((h2){ka[2], ka[3]}), 0.f);
        float s2 = FDOT2(qp[2], ((h2){ka[4], ka[5]}), 0.f);
        float s3 = FDOT2(qp[3], ((h2){ka[6], ka[7]}), 0.f);
        s0 = FDOT2(qp[4], ((h2){kb[0], kb[1]}), s0);
        s1 = FDOT2(qp[5], ((h2){kb[2], kb[3]}), s1);
        s2 = FDOT2(qp[6], ((h2){kb[4], kb[5]}), s2);
        s3 = FDOT2(qp[7], ((h2){kb[6], kb[7]}), s3);
        float sv = (s0 + s1) + (s2 + s3);
        pm[pass][m] = sv; mx = fmaxf(mx, sv);
      }
      float sum = 0.f;
      #pragma unroll
      for (int m = 0; m < 20; ++m) { pm[pass][m] = __expf(pm[pass][m] - mx); sum += pm[pass][m]; }
      float rs = 1.f / sum;
      #pragma unroll
      for (int m = 0; m < 20; ++m) pm[pass][m] *= rs;
    }
  }
  __syncthreads();

  #pragma unroll
  for (int pass = 0; pass < 3; ++pass) {
    int i = t + pass * 256;
    if (i < 640) {
      int e = i / 160, hh = (i / 20) % 8, n = i % 20;
      h2 c2[8];
      #pragma unroll
      for (int j = 0; j < 8; ++j) c2[j] = (h2){(_Float16)0.f, (_Float16)0.f};
      #pragma unroll
      for (int m = 0; m < 20; ++m) {
        const unsigned short* vr = &vs[(e * 20 + m) * 136 + hh * 16];
        f16x8 va = *(const f16x8*)vr;
        f16x8 vb = *(const f16x8*)(vr + 8);
        _Float16 ph = (_Float16)pm[pass][m];
        h2 pp = (h2){ph, ph};
        #pragma unroll
        for (int j = 0; j < 4; ++j) {
          c2[j]     += pp * (h2){va[2 * j], va[2 * j + 1]};
          c2[4 + j] += pp * (h2){vb[2 * j], vb[2 * j + 1]};
        }
      }
      f16x8 o0, o1;
      #pragma unroll
      for (int j = 0; j < 4; ++j) {
        o0[2 * j] = c2[j].x;     o0[2 * j + 1] = c2[j].y;
        o1[2 * j] = c2[4 + j].x; o1[2 * j + 1] = c2[4 + j].y;
      }
      unsigned short* cw = &ctx[(e * 20 + n) * 136 + hh * 16];
      *(f16x8*)cw = o0;
      *(f16x8*)(cw + 8) = o1;
    }
  }
  __syncthreads();

  {
    f32x4 acc[5][2];
    #pragma unroll
    for (int mt = 0; mt < 5; ++mt)
      #pragma unroll
      for (int i = 0; i < 2; ++i) acc[mt][i] = (f32x4){0.f, 0.f, 0.f, 0.f};
    #pragma unroll
    for (int kc = 0; kc < 4; ++kc) {
      f16x8 a[5], b[2];
      #pragma unroll
      for (int mt = 0; mt < 5; ++mt) {
        int g = mt * 16 + l15;
        a[mt] = *(const f16x8*)&ctx[g * 136 + kc * 32 + l4 * 8];
      }
      #pragma unroll
      for (int i = 0; i < 2; ++i) {
        int ntg = w * 2 + i;
        b[i] = *(const f16x8*)&woF[((ntg * 4 + kc) * 64 + l) * 8];
      }
      #pragma unroll
      for (int mt = 0; mt < 5; ++mt)
        #pragma unroll
        for (int i = 0; i < 2; ++i)
          acc[mt][i] = __builtin_amdgcn_mfma_f32_16x16x32_f16(a[mt], b[i], acc[mt][i], 0, 0, 0);
    }
    #pragma unroll
    for (int mt = 0; mt < 5; ++mt)
      #pragma unroll
      for (int i = 0; i < 2; ++i) {
        int col = (w * 2 + i) * 16 + l15;
        int gbase = mt * 16 + l4 * 4;
        #pragma unroll
        for (int j = 0; j < 4; ++j)
          scr[(gbase + j) * 136 + col] = f2h_bits(acc[mt][i][j]);
      }
  }
  __syncthreads();

  for (int r = w; r < 80; r += 4) {
    int e = r / 20, n = r % 20;
    const float* xrow = x + ((size_t)(eb + e) * 20 + n) * 128;
    float v0 = h2f_bits(scr[r * 136 + l])      + bo[l]      + xrow[l];
    float v1 = h2f_bits(scr[r * 136 + 64 + l]) + bo[64 + l] + xrow[64 + l];
    float s = v0 + v1, sq = v0 * v0 + v1 * v1;
    #pragma unroll
    for (int off = 32; off > 0; off >>= 1) { s += __shfl_xor(s, off); sq += __shfl_xor(sq, off); }
    float mean = s * (1.f / 128.f);
    float var  = sq * (1.f / 128.f) - mean * mean;
    float inv  = rsqrtf(var + 1e-5f);
    size_t ro = ((size_t)(eb + e) * 20 + n) * 128;
    xr[ro + l]      = f2bf((v0 - mean) * inv * n1w[l] + n1b[l]);
    xr[ro + 64 + l] = f2bf((v1 - mean) * inv * n1w[64 + l] + n1b[64 + l]);
  }
}

// ======================= FFN + LN2 v4b: quarter-col phases, (256,3) anti-spill ==================
__global__ __launch_bounds__(256, 3) void ffn_c(
    const unsigned short* __restrict__ xr,
    const unsigned short* __restrict__ w1F, const unsigned short* __restrict__ w2F,
    const float* __restrict__ b1, const float* __restrict__ b2,
    const float* __restrict__ n2w, const float* __restrict__ n2b,
    float* __restrict__ out)
{
  __shared__ __align__(16) unsigned short smem[2 * 64 * 136];
  unsigned short* xrb = smem;
  unsigned short* hq  = smem + 64 * 136;
  unsigned short* scr = hq;

  const int t = threadIdx.x;
  const int w = t >> 6, l = t & 63;
  const int l15 = l & 15, l4 = l >> 4;
  const size_t row0 = (size_t)blockIdx.x * 64;

  for (int i = t; i < 1024; i += 256) {
    int r = i >> 4, c8 = i & 15;
    *(bf16x8*)&xrb[r * 136 + c8 * 8] = *(const bf16x8*)&xr[(row0 + r) * 128 + c8 * 8];
  }
  __syncthreads();

  f32x4 acc2[4][2];
  #pragma unroll
  for (int mt = 0; mt < 4; ++mt)
    #pragma unroll
    for (int i = 0; i < 2; ++i) acc2[mt][i] = (f32x4){0.f, 0.f, 0.f, 0.f};

  #pragma unroll
  for (int ph = 0; ph < 4; ++ph) {
    f32x4 acc1[4][2];
    #pragma unroll
    for (int mt = 0; mt < 4; ++mt)
      #pragma unroll
      for (int i = 0; i < 2; ++i) acc1[mt][i] = (f32x4){0.f, 0.f, 0.f, 0.f};
    #pragma unroll
    for (int kc = 0; kc < 4; ++kc) {
      bf16x8 a[4];
      #pragma unroll
      for (int mt = 0; mt < 4; ++mt)
        a[mt] = *(const bf16x8*)&xrb[(mt * 16 + l15) * 136 + kc * 32 + l4 * 8];
      #pragma unroll
      for (int i = 0; i < 2; ++i) {
        int ntg = ph * 8 + w * 2 + i;
        bf16x8 b = *(const bf16x8*)&w1F[((ntg * 4 + kc) * 64 + l) * 8];
        #pragma unroll
        for (int mt = 0; mt < 4; ++mt)
          acc1[mt][i] = __builtin_amdgcn_mfma_f32_16x16x32_bf16(a[mt], b, acc1[mt][i], 0, 0, 0);
      }
    }
    #pragma unroll
    for (int i = 0; i < 2; ++i) {
      int lc = (w * 2 + i) * 16 + l15;
      float b1v = b1[(ph * 8 + w * 2 + i) * 16 + l15];
      #pragma unroll
      for (int mt = 0; mt < 4; ++mt)
        #pragma unroll
        for (int j = 0; j < 4; ++j) {
          float v = acc1[mt][i][j] + b1v;
          hq[(mt * 16 + l4 * 4 + j) * 136 + lc] = f2bf(gelu_t(v));
        }
    }
    __syncthreads();

    #pragma unroll
    for (int kk = 0; kk < 4; ++kk) {
      bf16x8 a[4];
      #pragma unroll
      for (int mt = 0; mt < 4; ++mt)
        a[mt] = *(const bf16x8*)&hq[(mt * 16 + l15) * 136 + kk * 32 + l4 * 8];
      #pragma unroll
      for (int i = 0; i < 2; ++i) {
        int ntg = w * 2 + i;
        int kcg = ph * 4 + kk;
        bf16x8 b = *(const bf16x8*)&w2F[((ntg * 16 + kcg) * 64 + l) * 8];
        #pragma unroll
        for (int mt = 0; mt < 4; ++mt)
          acc2[mt][i] = __builtin_amdgcn_mfma_f32_16x16x32_bf16(a[mt], b, acc2[mt][i], 0, 0, 0);
      }
    }
    __syncthreads();
  }

  #pragma unroll
  for (int mt = 0; mt < 4; ++mt)
    #pragma unroll
    for (int i = 0; i < 2; ++i) {
      int col = (w * 2 + i) * 16 + l15;
      int rbase = mt * 16 + l4 * 4;
      #pragma unroll
      for (int j = 0; j < 4; ++j)
        scr[(rbase + j) * 136 + col] = f2bf(acc2[mt][i][j]);
    }
  __syncthreads();

  for (int r = w; r < 64; r += 4) {
    float v0 = bf2f(scr[r * 136 + l])      + b2[l]      + bf2f(xrb[r * 136 + l]);
    float v1 = bf2f(scr[r * 136 + 64 + l]) + b2[64 + l] + bf2f(xrb[r * 136 + 64 + l]);
    float s = v0 + v1, sq = v0 * v0 + v1 * v1;
    #pragma unroll
    for (int off = 32; off > 0; off >>= 1) { s += __shfl_xor(s, off); sq += __shfl_xor(sq, off); }
    float mean = s * (1.f / 128.f);
    float var  = sq * (1.f / 128.f) - mean * mean;
    float inv  = rsqrtf(var + 1e-5f);
    out[(row0 + r) * 128 + l]      = (v0 - mean) * inv * n2w[l] + n2b[l];
    out[(row0 + r) * 128 + 64 + l] = (v1 - mean) * inv * n2w[64 + l] + n2b[64 + l];
  }
}

extern "C" void kernel_launch(void* const* d_in, const int* in_sizes, int n_in,
                              void* d_out, int out_size, void* d_ws, size_t ws_size,
                              hipStream_t stream) {
  const float* x     = (const float*)d_in[0];
  const float* wq    = (const float*)d_in[1];
  const float* wk    = (const float*)d_in[2];
  const float* wv    = (const float*)d_in[3];
  const float* lnq_w = (const float*)d_in[4];
  const float* lnq_b = (const float*)d_in[5];
  const float* lnk_w = (const float*)d_in[6];
  const float* lnk_b = (const float*)d_in[7];
  const float* lnv_w = (const float*)d_in[8];
  const float* lnv_b = (const float*)d_in[9];
  const float* rel   = (const float*)d_in[10];
  const float* gb    = (const float*)d_in[11];
  const float* alpha = (const float*)d_in[12];
  const float* wo    = (const float*)d_in[13];
  const float* bo    = (const float*)d_in[14];
  const float* w1    = (const float*)d_in[15];
  const float* b1    = (const float*)d_in[16];
  const float* w2    = (const float*)d_in[17];
  const float* b2    = (const float*)d_in[18];
  const float* n1w   = (const float*)d_in[19];
  const float* n1b   = (const float*)d_in[20];
  const float* n2w   = (const float*)d_in[21];
  const float* n2b   = (const float*)d_in[22];
  float* out = (float*)d_out;

  // ws: WcF | w1F | w2F | woF | biasT (602624 B) | xr (41.9 MB) | qP (41.9 MB). k,v planes in d_out.
  unsigned short* WcF = (unsigned short*)d_ws;     // 147456 us
  unsigned short* w1F = WcF + 147456;              // 65536
  unsigned short* w2F = w1F + 65536;               // 65536
  unsigned short* woF = w2F + 65536;               // 16384 (fp16)
  float* biasT = (float*)(woF + 16384);            // 3200 f32 -> ends at 602624 B
  unsigned short* xr = (unsigned short*)((char*)d_ws + 602624);

  const size_t NEED2 = 602624ULL + 41943040ULL;

  hipLaunchKernelGGL(prep2, dim3(584), dim3(256), 0, stream,
                     wq, wk, wv, w1, w2, wo, rel, gb, alpha, WcF, w1F, w2F, woF, biasT);

  unsigned short* qP = (unsigned short*)((char*)d_ws + NEED2);
  unsigned short* kP = (unsigned short*)d_out;
  unsigned short* vP = kP + (size_t)NROWS * 128;

  hipLaunchKernelGGL(conv_qkv, dim3(NROWS / 128), dim3(256), 0, stream,
                     x, WcF, lnq_w, lnq_b, lnk_w, lnk_b, lnv_w, lnv_b, qP, kP, vP);
  hipLaunchKernelGGL(attn_wo, dim3(NB / 4), dim3(256), 0, stream,
                     x, qP, kP, vP, woF, biasT, bo, n1w, n1b, xr);
  hipLaunchKernelGGL(ffn_c, dim3(NROWS / 64), dim3(256), 0, stream,
                     xr, w1F, w2F, b1, b2, n2w, n2b, out);
}

// Round 15
// 254.651 us; speedup vs baseline: 1.0585x; 1.0585x over previous
//
#include <hip/hip_runtime.h>
#include <hip/hip_bf16.h>
#include <math.h>

#define NB 8192
#define NN 20
#define DD 128
#define HH 8
#define FFD 512
#define NROWS (NB * NN)          // 163840 total rows

typedef __attribute__((ext_vector_type(8))) short bf16x8;
typedef __attribute__((ext_vector_type(4))) float f32x4;
typedef __attribute__((ext_vector_type(2))) _Float16 h2;
typedef __attribute__((ext_vector_type(8))) _Float16 f16x8;

#if defined(__has_builtin)
#if __has_builtin(__builtin_amdgcn_fdot2)
#define FDOT2(a, b, c) __builtin_amdgcn_fdot2((a), (b), (c), false)
#endif
#endif
#ifndef FDOT2
#define FDOT2(a, b, c) (fmaf((float)(a).x, (float)(b).x, fmaf((float)(a).y, (float)(b).y, (c))))
#endif

__device__ __forceinline__ unsigned short f2bf(float f) {
  union { __hip_bfloat16 h; unsigned short u; } cv; cv.h = __float2bfloat16(f); return cv.u;
}
__device__ __forceinline__ float bf2f(unsigned short u) {
  union { unsigned short u; __hip_bfloat16 h; } cv; cv.u = u; return __bfloat162float(cv.h);
}
__device__ __forceinline__ unsigned short f2h_bits(float f) {
  union { _Float16 h; unsigned short u; } cv; cv.h = (_Float16)f; return cv.u;
}
__device__ __forceinline__ float h2f_bits(unsigned short u) {
  union { unsigned short u; _Float16 h; } cv; cv.u = u; return (float)cv.h;
}
// gelu tanh-form, 8 ops
__device__ __forceinline__ float gelu_t(float v) {
  float t  = v * v;
  float u2 = v * fmaf(0.0713548162f, t, 1.5957691216f);
  float e  = __expf(u2);
  float r  = __builtin_amdgcn_rcpf(e + 1.0f);
  return fmaf(-v, r, v);
}
// async global->LDS, 16B/lane
__device__ __forceinline__ void gload16(const unsigned short* g, unsigned short* lds) {
  __builtin_amdgcn_global_load_lds(
      (const __attribute__((address_space(1))) unsigned int*)g,
      (__attribute__((address_space(3))) unsigned int*)lds, 16, 0, 0);
}

// ======================= prep: weight frag swizzle + bias fuse (frozen) =======================
__global__ __launch_bounds__(256) void prep2(
    const float* __restrict__ wq, const float* __restrict__ wk, const float* __restrict__ wv,
    const float* __restrict__ w1, const float* __restrict__ w2, const float* __restrict__ wo,
    const float* __restrict__ rel, const float* __restrict__ gb, const float* __restrict__ alpha,
    unsigned short* __restrict__ WcF, unsigned short* __restrict__ w1F,
    unsigned short* __restrict__ w2F, unsigned short* __restrict__ woF,
    float* __restrict__ biasT)
{
  int bid = blockIdx.x, t = threadIdx.x;
  if (bid < 288) {
    int nt = bid / 12, kc = bid % 12;
    for (int i = t; i < 512; i += 256) {
      int lane = i >> 3, j = i & 7;
      int k = kc * 32 + (lane >> 4) * 8 + j;
      int c = nt * 16 + (lane & 15);
      int kk = k >> 7, din = k & 127;
      int which = c >> 7, dout = c & 127;
      const float* w = (which == 0) ? wq : (which == 1) ? wk : wv;
      WcF[((nt * 12 + kc) * 64 + lane) * 8 + j] = f2bf(w[(dout * 128 + din) * 3 + kk]);
    }
  } else if (bid < 416) {
    int tt = bid - 288; int nt = tt / 4, kc = tt % 4;
    for (int i = t; i < 512; i += 256) {
      int lane = i >> 3, j = i & 7;
      int k = kc * 32 + (lane >> 4) * 8 + j;
      int c = nt * 16 + (lane & 15);
      w1F[((nt * 4 + kc) * 64 + lane) * 8 + j] = f2bf(w1[k * 512 + c]);
    }
  } else if (bid < 544) {
    int tt = bid - 416; int nt = tt / 16, kc = tt % 16;
    for (int i = t; i < 512; i += 256) {
      int lane = i >> 3, j = i & 7;
      int k = kc * 32 + (lane >> 4) * 8 + j;
      int c = nt * 16 + (lane & 15);
      w2F[((nt * 16 + kc) * 64 + lane) * 8 + j] = f2bf(w2[k * 128 + c]);
    }
  } else if (bid < 576) {
    int tt = bid - 544; int nt = tt / 4, kc = tt % 4;
    for (int i = t; i < 512; i += 256) {
      int lane = i >> 3, j = i & 7;
      int k = kc * 32 + (lane >> 4) * 8 + j;
      int c = nt * 16 + (lane & 15);
      woF[((nt * 4 + kc) * 64 + lane) * 8 + j] = f2h_bits(wo[k * 128 + c]);   // fp16
    }
  } else {
    int h = bid - 576; float a = alpha[0];
    for (int i = t; i < 400; i += 256) {
      int n = i / 20, m = i % 20;
      biasT[h * 400 + i] = rel[(n - m + 19) * 8 + h] + gb[h * 400 + i] * a;
    }
  }
}

// ======================= conv1d-QKV v6 (frozen): fused q/k/v, __syncthreads pipeline ============
__global__ __launch_bounds__(256, 3) void conv_qkv(
    const float* __restrict__ x, const unsigned short* __restrict__ WcF,
    const float* __restrict__ lnq_w, const float* __restrict__ lnq_b,
    const float* __restrict__ lnk_w, const float* __restrict__ lnk_b,
    const float* __restrict__ lnv_w, const float* __restrict__ lnv_b,
    unsigned short* __restrict__ qP, unsigned short* __restrict__ kP,
    unsigned short* __restrict__ vP)
{
  __shared__ __align__(16) unsigned short xA[130 * 136];
  __shared__ __align__(16) unsigned short Bb[2][4096];
  unsigned short* Obuf = &Bb[0][0];

  const int t = threadIdx.x;
  const int w = t >> 6, l = t & 63;
  const int l15 = l & 15, l4 = l >> 4;
  const long g0 = (long)blockIdx.x * 128;
  const int chunkA = w * 2, chunkB = w * 2 + 1;

  gload16(WcF + (size_t)(chunkA * 12) * 512 + l * 8, &Bb[0][chunkA * 512]);
  gload16(WcF + (size_t)(chunkB * 12) * 512 + l * 8, &Bb[0][chunkB * 512]);

  for (int i = t; i < 130 * 32; i += 256) {
    int r = i >> 5, c4 = i & 31;
    long g = g0 - 1 + r;
    long gc = g < 0 ? 0 : (g >= NROWS ? NROWS - 1 : g);
    float4 v = *(const float4*)(x + gc * 128 + c4 * 4);
    ushort4 pk; pk.x = f2bf(v.x); pk.y = f2bf(v.y); pk.z = f2bf(v.z); pk.w = f2bf(v.w);
    *(ushort4*)&xA[r * 136 + c4 * 4] = pk;
  }
  __syncthreads();   // Bb[0] + xA ready

  const int rA0 = w * 32 + l15;
  const int rA1 = rA0 + 16;
  const int nA0 = (int)((g0 + rA0) % 20);
  const int nA1 = (int)((g0 + rA1) % 20);
  bool mk0[3], mk1[3];
  mk0[0] = (nA0 != 0);  mk0[1] = true; mk0[2] = (nA0 != 19);
  mk1[0] = (nA1 != 0);  mk1[1] = true; mk1[2] = (nA1 != 19);

  const bf16x8 zz = {};
  for (int p = 0; p < 3; ++p) {
    const size_t Wpo = (size_t)p * 8 * 12 * 512;

    f32x4 acc[2][8];
    #pragma unroll
    for (int mt = 0; mt < 2; ++mt)
      #pragma unroll
      for (int nt = 0; nt < 8; ++nt) acc[mt][nt] = (f32x4){0.f, 0.f, 0.f, 0.f};

    for (int kc = 0; kc < 12; ++kc) {
      if (kc < 11) {
        int nb = (kc + 1) & 1;
        gload16(WcF + Wpo + (size_t)(chunkA * 12 + kc + 1) * 512 + l * 8, &Bb[nb][chunkA * 512]);
        gload16(WcF + Wpo + (size_t)(chunkB * 12 + kc + 1) * 512 + l * 8, &Bb[nb][chunkB * 512]);
      }
      const int kk = kc >> 2, k4 = kc & 3;
      bf16x8 a0 = *(const bf16x8*)&xA[(rA0 + kk) * 136 + k4 * 32 + l4 * 8]; if (!mk0[kk]) a0 = zz;
      bf16x8 a1 = *(const bf16x8*)&xA[(rA1 + kk) * 136 + k4 * 32 + l4 * 8]; if (!mk1[kk]) a1 = zz;
      const unsigned short* bb = &Bb[kc & 1][l * 8];
      #pragma unroll
      for (int nt = 0; nt < 8; ++nt) {
        bf16x8 b = *(const bf16x8*)(bb + nt * 512);
        acc[0][nt] = __builtin_amdgcn_mfma_f32_16x16x32_bf16(a0, b, acc[0][nt], 0, 0, 0);
        acc[1][nt] = __builtin_amdgcn_mfma_f32_16x16x32_bf16(a1, b, acc[1][nt], 0, 0, 0);
      }
      __syncthreads();
    }

    const float* lw = (p == 0) ? lnq_w : (p == 1) ? lnk_w : lnv_w;
    const float* lb = (p == 0) ? lnq_b : (p == 1) ? lnk_b : lnv_b;
    const float qs = (p == 0) ? 0.25f : 1.0f;
    unsigned short* plane = (p == 0) ? qP : (p == 1) ? kP : vP;
    float gw8[8], gb8[8];
    #pragma unroll
    for (int nt = 0; nt < 8; ++nt) { gw8[nt] = lw[nt * 16 + l15]; gb8[nt] = lb[nt * 16 + l15]; }

    float meanv[2][4], invv[2][4];
    #pragma unroll
    for (int mt = 0; mt < 2; ++mt) {
      float s[4], qq[4];
      #pragma unroll
      for (int j = 0; j < 4; ++j) {
        float a0 = 0.f, a1 = 0.f;
        #pragma unroll
        for (int nt = 0; nt < 8; ++nt) { float v = acc[mt][nt][j]; a0 += v; a1 = fmaf(v, v, a1); }
        s[j] = a0; qq[j] = a1;
      }
      #pragma unroll
      for (int off = 1; off < 16; off <<= 1) {
        #pragma unroll
        for (int j = 0; j < 4; ++j) { s[j] += __shfl_xor(s[j], off); qq[j] += __shfl_xor(qq[j], off); }
      }
      #pragma unroll
      for (int j = 0; j < 4; ++j) {
        float mean = s[j] * (1.f / 128.f);
        float var  = qq[j] * (1.f / 128.f) - mean * mean;
        meanv[mt][j] = mean;
        invv[mt][j]  = rsqrtf(var + 1e-5f);
      }
    }

    #pragma unroll
    for (int q = 0; q < 2; ++q) {
      #pragma unroll
      for (int mt = 0; mt < 2; ++mt)
        #pragma unroll
        for (int j = 0; j < 4; ++j) {
          int lr = w * 32 + mt * 16 + l4 * 4 + j;
          #pragma unroll
          for (int ntl = 0; ntl < 4; ++ntl) {
            int nt = q * 4 + ntl;
            Obuf[lr * 64 + ntl * 16 + l15] =
                f2bf((acc[mt][nt][j] - meanv[mt][j]) * invv[mt][j] * gw8[nt] + gb8[nt]);
          }
        }
      __syncthreads();
      #pragma unroll
      for (int it = 0; it < 4; ++it) {
        int i = t + it * 256;
        int r = i >> 3, c8 = i & 7;
        bf16x8 ob = *(const bf16x8*)&Obuf[r * 64 + c8 * 8];
        bf16x8 xr8 = *(const bf16x8*)&xA[(r + 1) * 136 + q * 64 + c8 * 8];
        unsigned short o[8];
        #pragma unroll
        for (int j = 0; j < 8; ++j)
          o[j] = f2h_bits((bf2f((unsigned short)xr8[j]) + bf2f((unsigned short)ob[j])) * qs);  // fp16
        *(bf16x8*)&plane[(g0 + r) * 128 + q * 64 + c8 * 8] = *(const bf16x8*)o;
      }
      __syncthreads();
    }

    if (p < 2) {
      size_t Wn = (size_t)(p + 1) * 8 * 12 * 512;
      gload16(WcF + Wn + (size_t)(chunkA * 12) * 512 + l * 8, &Bb[0][chunkA * 512]);
      gload16(WcF + Wn + (size_t)(chunkB * 12) * 512 + l * 8, &Bb[0][chunkB * 512]);
      __syncthreads();
    }
  }
}

// ======================= attn_wo v5 (frozen): FP16 data path, dot2/pk_fma =======================
__global__ __launch_bounds__(256, 3) void attn_wo(
    const float* __restrict__ x,
    const unsigned short* __restrict__ qP, const unsigned short* __restrict__ kP,
    const unsigned short* __restrict__ vP,
    const unsigned short* __restrict__ woF, const float* __restrict__ biasT,
    const float* __restrict__ bo,
    const float* __restrict__ n1w, const float* __restrict__ n1b,
    unsigned short* __restrict__ xr)
{
  __shared__ __align__(16) char smem[43520];
  unsigned short* ks  = (unsigned short*)smem;
  unsigned short* vs  = (unsigned short*)(smem + 21760);
  unsigned short* ctx = ks;
  unsigned short* scr = vs;

  const int t = threadIdx.x;
  const int w = t >> 6, l = t & 63;
  const int l15 = l & 15, l4 = l >> 4;
  const int eb = blockIdx.x * 4;

  for (int i = t; i < 2560; i += 256) {
    int proj = i / 1280, r = i % 1280;
    int e = r / 320, rr = r % 320;
    int n = rr / 16, c8 = rr % 16;
    const unsigned short* src = (proj == 0 ? kP : vP) + (((size_t)(eb + e) * 20 + n) * 128 + c8 * 8);
    unsigned short* dst = (proj == 0 ? ks : vs) + ((e * 20 + n) * 136 + c8 * 8);
    *(bf16x8*)dst = *(const bf16x8*)src;
  }
  __syncthreads();

  float pm[3][20];
  #pragma unroll
  for (int pass = 0; pass < 3; ++pass) {
    int i = t + pass * 256;
    if (i < 640) {
      int e = i / 160, hh = (i / 20) % 8, n = i % 20;
      const unsigned short* qr = qP + ((size_t)(eb + e) * 20 + n) * 128 + hh * 16;
      f16x8 qa = *(const f16x8*)qr;
      f16x8 qb = *(const f16x8*)(qr + 8);
      h2 qp[8];
      #pragma unroll
      for (int j = 0; j < 4; ++j) {
        qp[j]     = (h2){qa[2 * j], qa[2 * j + 1]};
        qp[4 + j] = (h2){qb[2 * j], qb[2 * j + 1]};
      }
      float bias[20];
      const float* bp = &biasT[(hh * 20 + n) * 20];
      #pragma unroll
      for (int m4 = 0; m4 < 5; ++m4) {
        float4 bv = *(const float4*)(bp + m4 * 4);
        bias[m4 * 4] = bv.x; bias[m4 * 4 + 1] = bv.y; bias[m4 * 4 + 2] = bv.z; bias[m4 * 4 + 3] = bv.w;
      }
      float mx = -1e30f;
      #pragma unroll
      for (int m = 0; m < 20; ++m) {
        const unsigned short* kr = &ks[(e * 20 + m) * 136 + hh * 16];
        f16x8 ka = *(const f16x8*)kr;
        f16x8 kb = *(const f16x8*)(kr + 8);
        float s0 = FDOT2(qp[0], ((h2){ka[0], ka[1]}), bias[m]);
        float s1 = FDOT2(qp[1], ((h2){ka[2], ka[3]}), 0.f);
        float s2 = FDOT2(qp[2], ((h2){ka[4], ka[5]}), 0.f);
        float s3 = FDOT2(qp[3], ((h2){ka[6], ka[7]}), 0.f);
        s0 = FDOT2(qp[4], ((h2){kb[0], kb[1]}), s0);
        s1 = FDOT2(qp[5], ((h2){kb[2], kb[3]}), s1);
        s2 = FDOT2(qp[6], ((h2){kb[4], kb[5]}), s2);
        s3 = FDOT2(qp[7], ((h2){kb[6], kb[7]}), s3);
        float sv = (s0 + s1) + (s2 + s3);
        pm[pass][m] = sv; mx = fmaxf(mx, sv);
      }
      float sum = 0.f;
      #pragma unroll
      for (int m = 0; m < 20; ++m) { pm[pass][m] = __expf(pm[pass][m] - mx); sum += pm[pass][m]; }
      float rs = 1.f / sum;
      #pragma unroll
      for (int m = 0; m < 20; ++m) pm[pass][m] *= rs;
    }
  }
  __syncthreads();

  #pragma unroll
  for (int pass = 0; pass < 3; ++pass) {
    int i = t + pass * 256;
    if (i < 640) {
      int e = i / 160, hh = (i / 20) % 8, n = i % 20;
      h2 c2[8];
      #pragma unroll
      for (int j = 0; j < 8; ++j) c2[j] = (h2){(_Float16)0.f, (_Float16)0.f};
      #pragma unroll
      for (int m = 0; m < 20; ++m) {
        const unsigned short* vr = &vs[(e * 20 + m) * 136 + hh * 16];
        f16x8 va = *(const f16x8*)vr;
        f16x8 vb = *(const f16x8*)(vr + 8);
        _Float16 ph = (_Float16)pm[pass][m];
        h2 pp = (h2){ph, ph};
        #pragma unroll
        for (int j = 0; j < 4; ++j) {
          c2[j]     += pp * (h2){va[2 * j], va[2 * j + 1]};
          c2[4 + j] += pp * (h2){vb[2 * j], vb[2 * j + 1]};
        }
      }
      f16x8 o0, o1;
      #pragma unroll
      for (int j = 0; j < 4; ++j) {
        o0[2 * j] = c2[j].x;     o0[2 * j + 1] = c2[j].y;
        o1[2 * j] = c2[4 + j].x; o1[2 * j + 1] = c2[4 + j].y;
      }
      unsigned short* cw = &ctx[(e * 20 + n) * 136 + hh * 16];
      *(f16x8*)cw = o0;
      *(f16x8*)(cw + 8) = o1;
    }
  }
  __syncthreads();

  {
    f32x4 acc[5][2];
    #pragma unroll
    for (int mt = 0; mt < 5; ++mt)
      #pragma unroll
      for (int i = 0; i < 2; ++i) acc[mt][i] = (f32x4){0.f, 0.f, 0.f, 0.f};
    #pragma unroll
    for (int kc = 0; kc < 4; ++kc) {
      f16x8 a[5], b[2];
      #pragma unroll
      for (int mt = 0; mt < 5; ++mt) {
        int g = mt * 16 + l15;
        a[mt] = *(const f16x8*)&ctx[g * 136 + kc * 32 + l4 * 8];
      }
      #pragma unroll
      for (int i = 0; i < 2; ++i) {
        int ntg = w * 2 + i;
        b[i] = *(const f16x8*)&woF[((ntg * 4 + kc) * 64 + l) * 8];
      }
      #pragma unroll
      for (int mt = 0; mt < 5; ++mt)
        #pragma unroll
        for (int i = 0; i < 2; ++i)
          acc[mt][i] = __builtin_amdgcn_mfma_f32_16x16x32_f16(a[mt], b[i], acc[mt][i], 0, 0, 0);
    }
    #pragma unroll
    for (int mt = 0; mt < 5; ++mt)
      #pragma unroll
      for (int i = 0; i < 2; ++i) {
        int col = (w * 2 + i) * 16 + l15;
        int gbase = mt * 16 + l4 * 4;
        #pragma unroll
        for (int j = 0; j < 4; ++j)
          scr[(gbase + j) * 136 + col] = f2h_bits(acc[mt][i][j]);
      }
  }
  __syncthreads();

  for (int r = w; r < 80; r += 4) {
    int e = r / 20, n = r % 20;
    const float* xrow = x + ((size_t)(eb + e) * 20 + n) * 128;
    float v0 = h2f_bits(scr[r * 136 + l])      + bo[l]      + xrow[l];
    float v1 = h2f_bits(scr[r * 136 + 64 + l]) + bo[64 + l] + xrow[64 + l];
    float s = v0 + v1, sq = v0 * v0 + v1 * v1;
    #pragma unroll
    for (int off = 32; off > 0; off >>= 1) { s += __shfl_xor(s, off); sq += __shfl_xor(sq, off); }
    float mean = s * (1.f / 128.f);
    float var  = sq * (1.f / 128.f) - mean * mean;
    float inv  = rsqrtf(var + 1e-5f);
    size_t ro = ((size_t)(eb + e) * 20 + n) * 128;
    xr[ro + l]      = f2bf((v0 - mean) * inv * n1w[l] + n1b[l]);
    xr[ro + 64 + l] = f2bf((v1 - mean) * inv * n1w[64 + l] + n1b[64 + l]);
  }
}

// ======================= FFN + LN2 v5: anti-spill (single-nt FFN1 substeps, (256,2)) ============
// Quarter-col phases as v4; FFN1 split into per-nt substeps so concurrent live regs =
// acc2(32) + acc1(16) + operands (~80 total) -> no scratch spill; occupancy LDS-limited (34.8KB).
__global__ __launch_bounds__(256, 2) void ffn_c(
    const unsigned short* __restrict__ xr,
    const unsigned short* __restrict__ w1F, const unsigned short* __restrict__ w2F,
    const float* __restrict__ b1, const float* __restrict__ b2,
    const float* __restrict__ n2w, const float* __restrict__ n2b,
    float* __restrict__ out)
{
  __shared__ __align__(16) unsigned short smem[2 * 64 * 136];
  unsigned short* xrb = smem;
  unsigned short* hq  = smem + 64 * 136;
  unsigned short* scr = hq;

  const int t = threadIdx.x;
  const int w = t >> 6, l = t & 63;
  const int l15 = l & 15, l4 = l >> 4;
  const size_t row0 = (size_t)blockIdx.x * 64;

  for (int i = t; i < 1024; i += 256) {
    int r = i >> 4, c8 = i & 15;
    *(bf16x8*)&xrb[r * 136 + c8 * 8] = *(const bf16x8*)&xr[(row0 + r) * 128 + c8 * 8];
  }
  __syncthreads();

  f32x4 acc2[4][2];
  #pragma unroll
  for (int mt = 0; mt < 4; ++mt)
    #pragma unroll
    for (int i = 0; i < 2; ++i) acc2[mt][i] = (f32x4){0.f, 0.f, 0.f, 0.f};

  #pragma unroll
  for (int ph = 0; ph < 4; ++ph) {
    // ---- FFN1 quarter, two single-nt substeps (acc1 only 4 f32x4 live) ----
    #pragma unroll
    for (int i = 0; i < 2; ++i) {
      f32x4 acc1[4];
      #pragma unroll
      for (int mt = 0; mt < 4; ++mt) acc1[mt] = (f32x4){0.f, 0.f, 0.f, 0.f};
      int ntg = ph * 8 + w * 2 + i;
      #pragma unroll
      for (int kc = 0; kc < 4; ++kc) {
        bf16x8 b = *(const bf16x8*)&w1F[((ntg * 4 + kc) * 64 + l) * 8];
        #pragma unroll
        for (int mt = 0; mt < 4; ++mt) {
          bf16x8 a = *(const bf16x8*)&xrb[(mt * 16 + l15) * 136 + kc * 32 + l4 * 8];
          acc1[mt] = __builtin_amdgcn_mfma_f32_16x16x32_bf16(a, b, acc1[mt], 0, 0, 0);
        }
      }
      int lc = (w * 2 + i) * 16 + l15;
      float b1v = b1[ntg * 16 + l15];
      #pragma unroll
      for (int mt = 0; mt < 4; ++mt)
        #pragma unroll
        for (int j = 0; j < 4; ++j) {
          float v = acc1[mt][j] + b1v;
          hq[(mt * 16 + l4 * 4 + j) * 136 + lc] = f2bf(gelu_t(v));
        }
    }
    __syncthreads();

    // ---- FFN2 partial: K = this quarter's 128 cols ----
    #pragma unroll
    for (int kk = 0; kk < 4; ++kk) {
      bf16x8 a[4];
      #pragma unroll
      for (int mt = 0; mt < 4; ++mt)
        a[mt] = *(const bf16x8*)&hq[(mt * 16 + l15) * 136 + kk * 32 + l4 * 8];
      #pragma unroll
      for (int i = 0; i < 2; ++i) {
        int ntg = w * 2 + i;
        int kcg = ph * 4 + kk;
        bf16x8 b = *(const bf16x8*)&w2F[((ntg * 16 + kcg) * 64 + l) * 8];
        #pragma unroll
        for (int mt = 0; mt < 4; ++mt)
          acc2[mt][i] = __builtin_amdgcn_mfma_f32_16x16x32_bf16(a[mt], b, acc2[mt][i], 0, 0, 0);
      }
    }
    __syncthreads();
  }

  #pragma unroll
  for (int mt = 0; mt < 4; ++mt)
    #pragma unroll
    for (int i = 0; i < 2; ++i) {
      int col = (w * 2 + i) * 16 + l15;
      int rbase = mt * 16 + l4 * 4;
      #pragma unroll
      for (int j = 0; j < 4; ++j)
        scr[(rbase + j) * 136 + col] = f2bf(acc2[mt][i][j]);
    }
  __syncthreads();

  for (int r = w; r < 64; r += 4) {
    float v0 = bf2f(scr[r * 136 + l])      + b2[l]      + bf2f(xrb[r * 136 + l]);
    float v1 = bf2f(scr[r * 136 + 64 + l]) + b2[64 + l] + bf2f(xrb[r * 136 + 64 + l]);
    float s = v0 + v1, sq = v0 * v0 + v1 * v1;
    #pragma unroll
    for (int off = 32; off > 0; off >>= 1) { s += __shfl_xor(s, off); sq += __shfl_xor(sq, off); }
    float mean = s * (1.f / 128.f);
    float var  = sq * (1.f / 128.f) - mean * mean;
    float inv  = rsqrtf(var + 1e-5f);
    out[(row0 + r) * 128 + l]      = (v0 - mean) * inv * n2w[l] + n2b[l];
    out[(row0 + r) * 128 + 64 + l] = (v1 - mean) * inv * n2w[64 + l] + n2b[64 + l];
  }
}

extern "C" void kernel_launch(void* const* d_in, const int* in_sizes, int n_in,
                              void* d_out, int out_size, void* d_ws, size_t ws_size,
                              hipStream_t stream) {
  const float* x     = (const float*)d_in[0];
  const float* wq    = (const float*)d_in[1];
  const float* wk    = (const float*)d_in[2];
  const float* wv    = (const float*)d_in[3];
  const float* lnq_w = (const float*)d_in[4];
  const float* lnq_b = (const float*)d_in[5];
  const float* lnk_w = (const float*)d_in[6];
  const float* lnk_b = (const float*)d_in[7];
  const float* lnv_w = (const float*)d_in[8];
  const float* lnv_b = (const float*)d_in[9];
  const float* rel   = (const float*)d_in[10];
  const float* gb    = (const float*)d_in[11];
  const float* alpha = (const float*)d_in[12];
  const float* wo    = (const float*)d_in[13];
  const float* bo    = (const float*)d_in[14];
  const float* w1    = (const float*)d_in[15];
  const float* b1    = (const float*)d_in[16];
  const float* w2    = (const float*)d_in[17];
  const float* b2    = (const float*)d_in[18];
  const float* n1w   = (const float*)d_in[19];
  const float* n1b   = (const float*)d_in[20];
  const float* n2w   = (const float*)d_in[21];
  const float* n2b   = (const float*)d_in[22];
  float* out = (float*)d_out;

  // ws: WcF | w1F | w2F | woF | biasT (602624 B) | xr (41.9 MB) | qP (41.9 MB). k,v planes in d_out.
  unsigned short* WcF = (unsigned short*)d_ws;     // 147456 us
  unsigned short* w1F = WcF + 147456;              // 65536
  unsigned short* w2F = w1F + 65536;               // 65536
  unsigned short* woF = w2F + 65536;               // 16384 (fp16)
  float* biasT = (float*)(woF + 16384);            // 3200 f32 -> ends at 602624 B
  unsigned short* xr = (unsigned short*)((char*)d_ws + 602624);

  const size_t NEED2 = 602624ULL + 41943040ULL;

  hipLaunchKernelGGL(prep2, dim3(584), dim3(256), 0, stream,
                     wq, wk, wv, w1, w2, wo, rel, gb, alpha, WcF, w1F, w2F, woF, biasT);

  unsigned short* qP = (unsigned short*)((char*)d_ws + NEED2);
  unsigned short* kP = (unsigned short*)d_out;
  unsigned short* vP = kP + (size_t)NROWS * 128;

  hipLaunchKernelGGL(conv_qkv, dim3(NROWS / 128), dim3(256), 0, stream,
                     x, WcF, lnq_w, lnq_b, lnk_w, lnk_b, lnv_w, lnv_b, qP, kP, vP);
  hipLaunchKernelGGL(attn_wo, dim3(NB / 4), dim3(256), 0, stream,
                     x, qP, kP, vP, woF, biasT, bo, n1w, n1b, xr);
  hipLaunchKernelGGL(ffn_c, dim3(NROWS / 64), dim3(256), 0, stream,
                     xr, w1F, w2F, b1, b2, n2w, n2b, out);
}

// Round 16
// 251.623 us; speedup vs baseline: 1.0712x; 1.0120x over previous
//
#include <hip/hip_runtime.h>
#include <hip/hip_bf16.h>
#include <math.h>

#define NB 8192
#define NN 20
#define DD 128
#define HH 8
#define FFD 512
#define NROWS (NB * NN)          // 163840 total rows

typedef __attribute__((ext_vector_type(8))) short bf16x8;
typedef __attribute__((ext_vector_type(4))) float f32x4;
typedef __attribute__((ext_vector_type(2))) _Float16 h2;
typedef __attribute__((ext_vector_type(8))) _Float16 f16x8;

#if defined(__has_builtin)
#if __has_builtin(__builtin_amdgcn_fdot2)
#define FDOT2(a, b, c) __builtin_amdgcn_fdot2((a), (b), (c), false)
#endif
#endif
#ifndef FDOT2
#define FDOT2(a, b, c) (fmaf((float)(a).x, (float)(b).x, fmaf((float)(a).y, (float)(b).y, (c))))
#endif

__device__ __forceinline__ unsigned short f2bf(float f) {
  union { __hip_bfloat16 h; unsigned short u; } cv; cv.h = __float2bfloat16(f); return cv.u;
}
__device__ __forceinline__ float bf2f(unsigned short u) {
  union { unsigned short u; __hip_bfloat16 h; } cv; cv.u = u; return __bfloat162float(cv.h);
}
__device__ __forceinline__ unsigned short f2h_bits(float f) {
  union { _Float16 h; unsigned short u; } cv; cv.h = (_Float16)f; return cv.u;
}
__device__ __forceinline__ float h2f_bits(unsigned short u) {
  union { unsigned short u; _Float16 h; } cv; cv.u = u; return (float)cv.h;
}
// gelu tanh-form, 8 ops
__device__ __forceinline__ float gelu_t(float v) {
  float t  = v * v;
  float u2 = v * fmaf(0.0713548162f, t, 1.5957691216f);
  float e  = __expf(u2);
  float r  = __builtin_amdgcn_rcpf(e + 1.0f);
  return fmaf(-v, r, v);
}
// async global->LDS, 16B/lane
__device__ __forceinline__ void gload16(const unsigned short* g, unsigned short* lds) {
  __builtin_amdgcn_global_load_lds(
      (const __attribute__((address_space(1))) unsigned int*)g,
      (__attribute__((address_space(3))) unsigned int*)lds, 16, 0, 0);
}

// ======================= prep: weight frag swizzle + bias fuse (frozen) =======================
__global__ __launch_bounds__(256) void prep2(
    const float* __restrict__ wq, const float* __restrict__ wk, const float* __restrict__ wv,
    const float* __restrict__ w1, const float* __restrict__ w2, const float* __restrict__ wo,
    const float* __restrict__ rel, const float* __restrict__ gb, const float* __restrict__ alpha,
    unsigned short* __restrict__ WcF, unsigned short* __restrict__ w1F,
    unsigned short* __restrict__ w2F, unsigned short* __restrict__ woF,
    float* __restrict__ biasT)
{
  int bid = blockIdx.x, t = threadIdx.x;
  if (bid < 288) {
    int nt = bid / 12, kc = bid % 12;
    for (int i = t; i < 512; i += 256) {
      int lane = i >> 3, j = i & 7;
      int k = kc * 32 + (lane >> 4) * 8 + j;
      int c = nt * 16 + (lane & 15);
      int kk = k >> 7, din = k & 127;
      int which = c >> 7, dout = c & 127;
      const float* w = (which == 0) ? wq : (which == 1) ? wk : wv;
      WcF[((nt * 12 + kc) * 64 + lane) * 8 + j] = f2bf(w[(dout * 128 + din) * 3 + kk]);
    }
  } else if (bid < 416) {
    int tt = bid - 288; int nt = tt / 4, kc = tt % 4;
    for (int i = t; i < 512; i += 256) {
      int lane = i >> 3, j = i & 7;
      int k = kc * 32 + (lane >> 4) * 8 + j;
      int c = nt * 16 + (lane & 15);
      w1F[((nt * 4 + kc) * 64 + lane) * 8 + j] = f2bf(w1[k * 512 + c]);
    }
  } else if (bid < 544) {
    int tt = bid - 416; int nt = tt / 16, kc = tt % 16;
    for (int i = t; i < 512; i += 256) {
      int lane = i >> 3, j = i & 7;
      int k = kc * 32 + (lane >> 4) * 8 + j;
      int c = nt * 16 + (lane & 15);
      w2F[((nt * 16 + kc) * 64 + lane) * 8 + j] = f2bf(w2[k * 128 + c]);
    }
  } else if (bid < 576) {
    int tt = bid - 544; int nt = tt / 4, kc = tt % 4;
    for (int i = t; i < 512; i += 256) {
      int lane = i >> 3, j = i & 7;
      int k = kc * 32 + (lane >> 4) * 8 + j;
      int c = nt * 16 + (lane & 15);
      woF[((nt * 4 + kc) * 64 + lane) * 8 + j] = f2h_bits(wo[k * 128 + c]);   // fp16
    }
  } else {
    int h = bid - 576; float a = alpha[0];
    for (int i = t; i < 400; i += 256) {
      int n = i / 20, m = i % 20;
      biasT[h * 400 + i] = rel[(n - m + 19) * 8 + h] + gb[h * 400 + i] * a;
    }
  }
}

// ======================= conv1d-QKV v7c: fenced counted-vmcnt two-barrier kc pipeline ===========
// Per kc: SB(0) -> bar1 (WAR) -> SB(0) -> issue slab kc+1 -> vmcnt(2) -> bar2 (RAW) -> SB(0)
// -> ds_read+MFMA. No vmcnt(0) drains inside the loop; slab kc gets a full iteration of cover.
__global__ __launch_bounds__(256, 3) void conv_qkv(
    const float* __restrict__ x, const unsigned short* __restrict__ WcF,
    const float* __restrict__ lnq_w, const float* __restrict__ lnq_b,
    const float* __restrict__ lnk_w, const float* __restrict__ lnk_b,
    const float* __restrict__ lnv_w, const float* __restrict__ lnv_b,
    unsigned short* __restrict__ qP, unsigned short* __restrict__ kP,
    unsigned short* __restrict__ vP)
{
  __shared__ __align__(16) unsigned short xA[130 * 136];
  __shared__ __align__(16) unsigned short Bb[2][4096];
  unsigned short* Obuf = &Bb[0][0];

  const int t = threadIdx.x;
  const int w = t >> 6, l = t & 63;
  const int l15 = l & 15, l4 = l >> 4;
  const long g0 = (long)blockIdx.x * 128;
  const int chunkA = w * 2, chunkB = w * 2 + 1;

  gload16(WcF + (size_t)(chunkA * 12) * 512 + l * 8, &Bb[0][chunkA * 512]);
  gload16(WcF + (size_t)(chunkB * 12) * 512 + l * 8, &Bb[0][chunkB * 512]);

  for (int i = t; i < 130 * 32; i += 256) {
    int r = i >> 5, c4 = i & 31;
    long g = g0 - 1 + r;
    long gc = g < 0 ? 0 : (g >= NROWS ? NROWS - 1 : g);
    float4 v = *(const float4*)(x + gc * 128 + c4 * 4);
    ushort4 pk; pk.x = f2bf(v.x); pk.y = f2bf(v.y); pk.z = f2bf(v.z); pk.w = f2bf(v.w);
    *(ushort4*)&xA[r * 136 + c4 * 4] = pk;
  }
  __syncthreads();   // full drain: Bb[0] + xA ready, vmcnt=0 in every wave

  const int rA0 = w * 32 + l15;
  const int rA1 = rA0 + 16;
  const int nA0 = (int)((g0 + rA0) % 20);
  const int nA1 = (int)((g0 + rA1) % 20);
  bool mk0[3], mk1[3];
  mk0[0] = (nA0 != 0);  mk0[1] = true; mk0[2] = (nA0 != 19);
  mk1[0] = (nA1 != 0);  mk1[1] = true; mk1[2] = (nA1 != 19);

  const bf16x8 zz = {};
  for (int p = 0; p < 3; ++p) {
    const size_t Wpo = (size_t)p * 8 * 12 * 512;

    f32x4 acc[2][8];
    #pragma unroll
    for (int mt = 0; mt < 2; ++mt)
      #pragma unroll
      for (int nt = 0; nt < 8; ++nt) acc[mt][nt] = (f32x4){0.f, 0.f, 0.f, 0.f};

    for (int kc = 0; kc < 12; ++kc) {
      // ---- fenced two-barrier pipeline step ----
      __builtin_amdgcn_sched_barrier(0);          // pin iter kc-1 reads ABOVE bar1
      __builtin_amdgcn_s_barrier();               // bar1: WAR on buf[(kc+1)&1]
      __builtin_amdgcn_sched_barrier(0);          // pin issues BELOW bar1
      if (kc < 11) {
        int nb = (kc + 1) & 1;
        gload16(WcF + Wpo + (size_t)(chunkA * 12 + kc + 1) * 512 + l * 8, &Bb[nb][chunkA * 512]);
        gload16(WcF + Wpo + (size_t)(chunkB * 12 + kc + 1) * 512 + l * 8, &Bb[nb][chunkB * 512]);
        asm volatile("s_waitcnt vmcnt(2)" ::: "memory");   // own slab kc landed; kc+1 in flight
      } else {
        asm volatile("s_waitcnt vmcnt(0)" ::: "memory");   // last slab: full wait
      }
      __builtin_amdgcn_s_barrier();               // bar2: RAW — all waves' slab kc visible
      __builtin_amdgcn_sched_barrier(0);          // pin reads BELOW bar2 (rule #18)
      // ---- compute slab kc ----
      const int kk = kc >> 2, k4 = kc & 3;
      bf16x8 a0 = *(const bf16x8*)&xA[(rA0 + kk) * 136 + k4 * 32 + l4 * 8]; if (!mk0[kk]) a0 = zz;
      bf16x8 a1 = *(const bf16x8*)&xA[(rA1 + kk) * 136 + k4 * 32 + l4 * 8]; if (!mk1[kk]) a1 = zz;
      const unsigned short* bb = &Bb[kc & 1][l * 8];
      #pragma unroll
      for (int nt = 0; nt < 8; ++nt) {
        bf16x8 b = *(const bf16x8*)(bb + nt * 512);
        acc[0][nt] = __builtin_amdgcn_mfma_f32_16x16x32_bf16(a0, b, acc[0][nt], 0, 0, 0);
        acc[1][nt] = __builtin_amdgcn_mfma_f32_16x16x32_bf16(a1, b, acc[1][nt], 0, 0, 0);
      }
    }
    __syncthreads();   // full drain + barrier before Obuf aliases Bb

    const float* lw = (p == 0) ? lnq_w : (p == 1) ? lnk_w : lnv_w;
    const float* lb = (p == 0) ? lnq_b : (p == 1) ? lnk_b : lnv_b;
    const float qs = (p == 0) ? 0.25f : 1.0f;
    unsigned short* plane = (p == 0) ? qP : (p == 1) ? kP : vP;
    float gw8[8], gb8[8];
    #pragma unroll
    for (int nt = 0; nt < 8; ++nt) { gw8[nt] = lw[nt * 16 + l15]; gb8[nt] = lb[nt * 16 + l15]; }

    float meanv[2][4], invv[2][4];
    #pragma unroll
    for (int mt = 0; mt < 2; ++mt) {
      float s[4], qq[4];
      #pragma unroll
      for (int j = 0; j < 4; ++j) {
        float a0 = 0.f, a1 = 0.f;
        #pragma unroll
        for (int nt = 0; nt < 8; ++nt) { float v = acc[mt][nt][j]; a0 += v; a1 = fmaf(v, v, a1); }
        s[j] = a0; qq[j] = a1;
      }
      #pragma unroll
      for (int off = 1; off < 16; off <<= 1) {
        #pragma unroll
        for (int j = 0; j < 4; ++j) { s[j] += __shfl_xor(s[j], off); qq[j] += __shfl_xor(qq[j], off); }
      }
      #pragma unroll
      for (int j = 0; j < 4; ++j) {
        float mean = s[j] * (1.f / 128.f);
        float var  = qq[j] * (1.f / 128.f) - mean * mean;
        meanv[mt][j] = mean;
        invv[mt][j]  = rsqrtf(var + 1e-5f);
      }
    }

    #pragma unroll
    for (int q = 0; q < 2; ++q) {
      #pragma unroll
      for (int mt = 0; mt < 2; ++mt)
        #pragma unroll
        for (int j = 0; j < 4; ++j) {
          int lr = w * 32 + mt * 16 + l4 * 4 + j;
          #pragma unroll
          for (int ntl = 0; ntl < 4; ++ntl) {
            int nt = q * 4 + ntl;
            Obuf[lr * 64 + ntl * 16 + l15] =
                f2bf((acc[mt][nt][j] - meanv[mt][j]) * invv[mt][j] * gw8[nt] + gb8[nt]);
          }
        }
      __syncthreads();
      #pragma unroll
      for (int it = 0; it < 4; ++it) {
        int i = t + it * 256;
        int r = i >> 3, c8 = i & 7;
        bf16x8 ob = *(const bf16x8*)&Obuf[r * 64 + c8 * 8];
        bf16x8 xr8 = *(const bf16x8*)&xA[(r + 1) * 136 + q * 64 + c8 * 8];
        unsigned short o[8];
        #pragma unroll
        for (int j = 0; j < 8; ++j)
          o[j] = f2h_bits((bf2f((unsigned short)xr8[j]) + bf2f((unsigned short)ob[j])) * qs);  // fp16
        *(bf16x8*)&plane[(g0 + r) * 128 + q * 64 + c8 * 8] = *(const bf16x8*)o;
      }
      __syncthreads();
    }

    if (p < 2) {
      size_t Wn = (size_t)(p + 1) * 8 * 12 * 512;
      gload16(WcF + Wn + (size_t)(chunkA * 12) * 512 + l * 8, &Bb[0][chunkA * 512]);
      gload16(WcF + Wn + (size_t)(chunkB * 12) * 512 + l * 8, &Bb[0][chunkB * 512]);
      __syncthreads();   // drains: buf0 full, vmcnt=0 entering next projection's loop
    }
  }
}

// ======================= attn_wo v5 (frozen): FP16 data path, dot2/pk_fma =======================
__global__ __launch_bounds__(256, 3) void attn_wo(
    const float* __restrict__ x,
    const unsigned short* __restrict__ qP, const unsigned short* __restrict__ kP,
    const unsigned short* __restrict__ vP,
    const unsigned short* __restrict__ woF, const float* __restrict__ biasT,
    const float* __restrict__ bo,
    const float* __restrict__ n1w, const float* __restrict__ n1b,
    unsigned short* __restrict__ xr)
{
  __shared__ __align__(16) char smem[43520];
  unsigned short* ks  = (unsigned short*)smem;
  unsigned short* vs  = (unsigned short*)(smem + 21760);
  unsigned short* ctx = ks;
  unsigned short* scr = vs;

  const int t = threadIdx.x;
  const int w = t >> 6, l = t & 63;
  const int l15 = l & 15, l4 = l >> 4;
  const int eb = blockIdx.x * 4;

  for (int i = t; i < 2560; i += 256) {
    int proj = i / 1280, r = i % 1280;
    int e = r / 320, rr = r % 320;
    int n = rr / 16, c8 = rr % 16;
    const unsigned short* src = (proj == 0 ? kP : vP) + (((size_t)(eb + e) * 20 + n) * 128 + c8 * 8);
    unsigned short* dst = (proj == 0 ? ks : vs) + ((e * 20 + n) * 136 + c8 * 8);
    *(bf16x8*)dst = *(const bf16x8*)src;
  }
  __syncthreads();

  float pm[3][20];
  #pragma unroll
  for (int pass = 0; pass < 3; ++pass) {
    int i = t + pass * 256;
    if (i < 640) {
      int e = i / 160, hh = (i / 20) % 8, n = i % 20;
      const unsigned short* qr = qP + ((size_t)(eb + e) * 20 + n) * 128 + hh * 16;
      f16x8 qa = *(const f16x8*)qr;
      f16x8 qb = *(const f16x8*)(qr + 8);
      h2 qp[8];
      #pragma unroll
      for (int j = 0; j < 4; ++j) {
        qp[j]     = (h2){qa[2 * j], qa[2 * j + 1]};
        qp[4 + j] = (h2){qb[2 * j], qb[2 * j + 1]};
      }
      float bias[20];
      const float* bp = &biasT[(hh * 20 + n) * 20];
      #pragma unroll
      for (int m4 = 0; m4 < 5; ++m4) {
        float4 bv = *(const float4*)(bp + m4 * 4);
        bias[m4 * 4] = bv.x; bias[m4 * 4 + 1] = bv.y; bias[m4 * 4 + 2] = bv.z; bias[m4 * 4 + 3] = bv.w;
      }
      float mx = -1e30f;
      #pragma unroll
      for (int m = 0; m < 20; ++m) {
        const unsigned short* kr = &ks[(e * 20 + m) * 136 + hh * 16];
        f16x8 ka = *(const f16x8*)kr;
        f16x8 kb = *(const f16x8*)(kr + 8);
        float s0 = FDOT2(qp[0], ((h2){ka[0], ka[1]}), bias[m]);
        float s1 = FDOT2(qp[1], ((h2){ka[2], ka[3]}), 0.f);
        float s2 = FDOT2(qp[2], ((h2){ka[4], ka[5]}), 0.f);
        float s3 = FDOT2(qp[3], ((h2){ka[6], ka[7]}), 0.f);
        s0 = FDOT2(qp[4], ((h2){kb[0], kb[1]}), s0);
        s1 = FDOT2(qp[5], ((h2){kb[2], kb[3]}), s1);
        s2 = FDOT2(qp[6], ((h2){kb[4], kb[5]}), s2);
        s3 = FDOT2(qp[7], ((h2){kb[6], kb[7]}), s3);
        float sv = (s0 + s1) + (s2 + s3);
        pm[pass][m] = sv; mx = fmaxf(mx, sv);
      }
      float sum = 0.f;
      #pragma unroll
      for (int m = 0; m < 20; ++m) { pm[pass][m] = __expf(pm[pass][m] - mx); sum += pm[pass][m]; }
      float rs = 1.f / sum;
      #pragma unroll
      for (int m = 0; m < 20; ++m) pm[pass][m] *= rs;
    }
  }
  __syncthreads();

  #pragma unroll
  for (int pass = 0; pass < 3; ++pass) {
    int i = t + pass * 256;
    if (i < 640) {
      int e = i / 160, hh = (i / 20) % 8, n = i % 20;
      h2 c2[8];
      #pragma unroll
      for (int j = 0; j < 8; ++j) c2[j] = (h2){(_Float16)0.f, (_Float16)0.f};
      #pragma unroll
      for (int m = 0; m < 20; ++m) {
        const unsigned short* vr = &vs[(e * 20 + m) * 136 + hh * 16];
        f16x8 va = *(const f16x8*)vr;
        f16x8 vb = *(const f16x8*)(vr + 8);
        _Float16 ph = (_Float16)pm[pass][m];
        h2 pp = (h2){ph, ph};
        #pragma unroll
        for (int j = 0; j < 4; ++j) {
          c2[j]     += pp * (h2){va[2 * j], va[2 * j + 1]};
          c2[4 + j] += pp * (h2){vb[2 * j], vb[2 * j + 1]};
        }
      }
      f16x8 o0, o1;
      #pragma unroll
      for (int j = 0; j < 4; ++j) {
        o0[2 * j] = c2[j].x;     o0[2 * j + 1] = c2[j].y;
        o1[2 * j] = c2[4 + j].x; o1[2 * j + 1] = c2[4 + j].y;
      }
      unsigned short* cw = &ctx[(e * 20 + n) * 136 + hh * 16];
      *(f16x8*)cw = o0;
      *(f16x8*)(cw + 8) = o1;
    }
  }
  __syncthreads();

  {
    f32x4 acc[5][2];
    #pragma unroll
    for (int mt = 0; mt < 5; ++mt)
      #pragma unroll
      for (int i = 0; i < 2; ++i) acc[mt][i] = (f32x4){0.f, 0.f, 0.f, 0.f};
    #pragma unroll
    for (int kc = 0; kc < 4; ++kc) {
      f16x8 a[5], b[2];
      #pragma unroll
      for (int mt = 0; mt < 5; ++mt) {
        int g = mt * 16 + l15;
        a[mt] = *(const f16x8*)&ctx[g * 136 + kc * 32 + l4 * 8];
      }
      #pragma unroll
      for (int i = 0; i < 2; ++i) {
        int ntg = w * 2 + i;
        b[i] = *(const f16x8*)&woF[((ntg * 4 + kc) * 64 + l) * 8];
      }
      #pragma unroll
      for (int mt = 0; mt < 5; ++mt)
        #pragma unroll
        for (int i = 0; i < 2; ++i)
          acc[mt][i] = __builtin_amdgcn_mfma_f32_16x16x32_f16(a[mt], b[i], acc[mt][i], 0, 0, 0);
    }
    #pragma unroll
    for (int mt = 0; mt < 5; ++mt)
      #pragma unroll
      for (int i = 0; i < 2; ++i) {
        int col = (w * 2 + i) * 16 + l15;
        int gbase = mt * 16 + l4 * 4;
        #pragma unroll
        for (int j = 0; j < 4; ++j)
          scr[(gbase + j) * 136 + col] = f2h_bits(acc[mt][i][j]);
      }
  }
  __syncthreads();

  for (int r = w; r < 80; r += 4) {
    int e = r / 20, n = r % 20;
    const float* xrow = x + ((size_t)(eb + e) * 20 + n) * 128;
    float v0 = h2f_bits(scr[r * 136 + l])      + bo[l]      + xrow[l];
    float v1 = h2f_bits(scr[r * 136 + 64 + l]) + bo[64 + l] + xrow[64 + l];
    float s = v0 + v1, sq = v0 * v0 + v1 * v1;
    #pragma unroll
    for (int off = 32; off > 0; off >>= 1) { s += __shfl_xor(s, off); sq += __shfl_xor(sq, off); }
    float mean = s * (1.f / 128.f);
    float var  = sq * (1.f / 128.f) - mean * mean;
    float inv  = rsqrtf(var + 1e-5f);
    size_t ro = ((size_t)(eb + e) * 20 + n) * 128;
    xr[ro + l]      = f2bf((v0 - mean) * inv * n1w[l] + n1b[l]);
    xr[ro + 64 + l] = f2bf((v1 - mean) * inv * n1w[64 + l] + n1b[64 + l]);
  }
}

// ======================= FFN + LN2 v5 (frozen): anti-spill single-nt FFN1, (256,2) ==============
__global__ __launch_bounds__(256, 2) void ffn_c(
    const unsigned short* __restrict__ xr,
    const unsigned short* __restrict__ w1F, const unsigned short* __restrict__ w2F,
    const float* __restrict__ b1, const float* __restrict__ b2,
    const float* __restrict__ n2w, const float* __restrict__ n2b,
    float* __restrict__ out)
{
  __shared__ __align__(16) unsigned short smem[2 * 64 * 136];
  unsigned short* xrb = smem;
  unsigned short* hq  = smem + 64 * 136;
  unsigned short* scr = hq;

  const int t = threadIdx.x;
  const int w = t >> 6, l = t & 63;
  const int l15 = l & 15, l4 = l >> 4;
  const size_t row0 = (size_t)blockIdx.x * 64;

  for (int i = t; i < 1024; i += 256) {
    int r = i >> 4, c8 = i & 15;
    *(bf16x8*)&xrb[r * 136 + c8 * 8] = *(const bf16x8*)&xr[(row0 + r) * 128 + c8 * 8];
  }
  __syncthreads();

  f32x4 acc2[4][2];
  #pragma unroll
  for (int mt = 0; mt < 4; ++mt)
    #pragma unroll
    for (int i = 0; i < 2; ++i) acc2[mt][i] = (f32x4){0.f, 0.f, 0.f, 0.f};

  #pragma unroll
  for (int ph = 0; ph < 4; ++ph) {
    #pragma unroll
    for (int i = 0; i < 2; ++i) {
      f32x4 acc1[4];
      #pragma unroll
      for (int mt = 0; mt < 4; ++mt) acc1[mt] = (f32x4){0.f, 0.f, 0.f, 0.f};
      int ntg = ph * 8 + w * 2 + i;
      #pragma unroll
      for (int kc = 0; kc < 4; ++kc) {
        bf16x8 b = *(const bf16x8*)&w1F[((ntg * 4 + kc) * 64 + l) * 8];
        #pragma unroll
        for (int mt = 0; mt < 4; ++mt) {
          bf16x8 a = *(const bf16x8*)&xrb[(mt * 16 + l15) * 136 + kc * 32 + l4 * 8];
          acc1[mt] = __builtin_amdgcn_mfma_f32_16x16x32_bf16(a, b, acc1[mt], 0, 0, 0);
        }
      }
      int lc = (w * 2 + i) * 16 + l15;
      float b1v = b1[ntg * 16 + l15];
      #pragma unroll
      for (int mt = 0; mt < 4; ++mt)
        #pragma unroll
        for (int j = 0; j < 4; ++j) {
          float v = acc1[mt][j] + b1v;
          hq[(mt * 16 + l4 * 4 + j) * 136 + lc] = f2bf(gelu_t(v));
        }
    }
    __syncthreads();

    #pragma unroll
    for (int kk = 0; kk < 4; ++kk) {
      bf16x8 a[4];
      #pragma unroll
      for (int mt = 0; mt < 4; ++mt)
        a[mt] = *(const bf16x8*)&hq[(mt * 16 + l15) * 136 + kk * 32 + l4 * 8];
      #pragma unroll
      for (int i = 0; i < 2; ++i) {
        int ntg = w * 2 + i;
        int kcg = ph * 4 + kk;
        bf16x8 b = *(const bf16x8*)&w2F[((ntg * 16 + kcg) * 64 + l) * 8];
        #pragma unroll
        for (int mt = 0; mt < 4; ++mt)
          acc2[mt][i] = __builtin_amdgcn_mfma_f32_16x16x32_bf16(a[mt], b, acc2[mt][i], 0, 0, 0);
      }
    }
    __syncthreads();
  }

  #pragma unroll
  for (int mt = 0; mt < 4; ++mt)
    #pragma unroll
    for (int i = 0; i < 2; ++i) {
      int col = (w * 2 + i) * 16 + l15;
      int rbase = mt * 16 + l4 * 4;
      #pragma unroll
      for (int j = 0; j < 4; ++j)
        scr[(rbase + j) * 136 + col] = f2bf(acc2[mt][i][j]);
    }
  __syncthreads();

  for (int r = w; r < 64; r += 4) {
    float v0 = bf2f(scr[r * 136 + l])      + b2[l]      + bf2f(xrb[r * 136 + l]);
    float v1 = bf2f(scr[r * 136 + 64 + l]) + b2[64 + l] + bf2f(xrb[r * 136 + 64 + l]);
    float s = v0 + v1, sq = v0 * v0 + v1 * v1;
    #pragma unroll
    for (int off = 32; off > 0; off >>= 1) { s += __shfl_xor(s, off); sq += __shfl_xor(sq, off); }
    float mean = s * (1.f / 128.f);
    float var  = sq * (1.f / 128.f) - mean * mean;
    float inv  = rsqrtf(var + 1e-5f);
    out[(row0 + r) * 128 + l]      = (v0 - mean) * inv * n2w[l] + n2b[l];
    out[(row0 + r) * 128 + 64 + l] = (v1 - mean) * inv * n2w[64 + l] + n2b[64 + l];
  }
}

extern "C" void kernel_launch(void* const* d_in, const int* in_sizes, int n_in,
                              void* d_out, int out_size, void* d_ws, size_t ws_size,
                              hipStream_t stream) {
  const float* x     = (const float*)d_in[0];
  const float* wq    = (const float*)d_in[1];
  const float* wk    = (const float*)d_in[2];
  const float* wv    = (const float*)d_in[3];
  const float* lnq_w = (const float*)d_in[4];
  const float* lnq_b = (const float*)d_in[5];
  const float* lnk_w = (const float*)d_in[6];
  const float* lnk_b = (const float*)d_in[7];
  const float* lnv_w = (const float*)d_in[8];
  const float* lnv_b = (const float*)d_in[9];
  const float* rel   = (const float*)d_in[10];
  const float* gb    = (const float*)d_in[11];
  const float* alpha = (const float*)d_in[12];
  const float* wo    = (const float*)d_in[13];
  const float* bo    = (const float*)d_in[14];
  const float* w1    = (const float*)d_in[15];
  const float* b1    = (const float*)d_in[16];
  const float* w2    = (const float*)d_in[17];
  const float* b2    = (const float*)d_in[18];
  const float* n1w   = (const float*)d_in[19];
  const float* n1b   = (const float*)d_in[20];
  const float* n2w   = (const float*)d_in[21];
  const float* n2b   = (const float*)d_in[22];
  float* out = (float*)d_out;

  // ws: WcF | w1F | w2F | woF | biasT (602624 B) | xr (41.9 MB) | qP (41.9 MB). k,v planes in d_out.
  unsigned short* WcF = (unsigned short*)d_ws;     // 147456 us
  unsigned short* w1F = WcF + 147456;              // 65536
  unsigned short* w2F = w1F + 65536;               // 65536
  unsigned short* woF = w2F + 65536;               // 16384 (fp16)
  float* biasT = (float*)(woF + 16384);            // 3200 f32 -> ends at 602624 B
  unsigned short* xr = (unsigned short*)((char*)d_ws + 602624);

  const size_t NEED2 = 602624ULL + 41943040ULL;

  hipLaunchKernelGGL(prep2, dim3(584), dim3(256), 0, stream,
                     wq, wk, wv, w1, w2, wo, rel, gb, alpha, WcF, w1F, w2F, woF, biasT);

  unsigned short* qP = (unsigned short*)((char*)d_ws + NEED2);
  unsigned short* kP = (unsigned short*)d_out;
  unsigned short* vP = kP + (size_t)NROWS * 128;

  hipLaunchKernelGGL(conv_qkv, dim3(NROWS / 128), dim3(256), 0, stream,
                     x, WcF, lnq_w, lnq_b, lnk_w, lnk_b, lnv_w, lnv_b, qP, kP, vP);
  hipLaunchKernelGGL(attn_wo, dim3(NB / 4), dim3(256), 0, stream,
                     x, qP, kP, vP, woF, biasT, bo, n1w, n1b, xr);
  hipLaunchKernelGGL(ffn_c, dim3(NROWS / 64), dim3(256), 0, stream,
                     xr, w1F, w2F, b1, b2, n2w, n2b, out);
}